// Round 5
// baseline (485.047 us; speedup 1.0000x reference)
//
#include <hip/hip_runtime.h>

// Problem constants
#define B_   1024
#define E_   200
#define NE_  50000
#define OC_  32
#define FW_  9
#define WP_  192
#define FCIN 6144   // OC*WP
#define CATK 400    // E+R
#define KDIM 288    // OC*FW

typedef __attribute__((ext_vector_type(8))) short short8;
typedef __attribute__((ext_vector_type(4))) float floatx4;
typedef __attribute__((ext_vector_type(4))) unsigned short ushort4v;

static __device__ __forceinline__ float bf2f(unsigned short u) {
  return __uint_as_float(((unsigned)u) << 16);
}
static __device__ __forceinline__ unsigned short f2bf(float f) {
  unsigned u = __float_as_uint(f);
  u += 0x7FFFu + ((u >> 16) & 1u);   // RNE
  return (unsigned short)(u >> 16);
}

// ---------------- fused prep: gather + 3 transposes (entity cvt moved to k_conv) ----------------
#define PREP_GATH_BLKS  2400   // (B*CATK + B*E)/256 exactly
#define PREP_W1_BLKS    28     // (4 x 7)
#define PREP_FC1_BLKS   20     // (5 x 4)
#define PREP_FCW_BLKS   384    // (4 x 96)
#define PREP_R2 (PREP_GATH_BLKS)
#define PREP_R3 (PREP_R2 + PREP_W1_BLKS)
#define PREP_R4 (PREP_R3 + PREP_FC1_BLKS)
#define PREP_TOTAL (PREP_R4 + PREP_FCW_BLKS)   // 2832

// LDS tile transpose+pad+convert: in[k*N+n] fp32 -> out[n*K+k] bf16 (n<Npad).
static __device__ __forceinline__ void transpose_region(
    const float* __restrict__ in, unsigned short* __restrict__ out,
    int N, int Npad, int K, int bx, int by,
    unsigned short (*lds)[65]) {
  int n0 = bx * 64, k0 = by * 64;
  int tx = threadIdx.x & 63, ty = threadIdx.x >> 6;   // ty in 0..3
#pragma unroll
  for (int kk = 0; kk < 16; kk++) {
    int k = k0 + ty + 4 * kk;
    int n = n0 + tx;
    unsigned short v = 0;
    if (k < K && n < N) v = f2bf(in[(long)k * N + n]);
    lds[ty + 4 * kk][tx] = v;
  }
  __syncthreads();
#pragma unroll
  for (int kk = 0; kk < 16; kk++) {
    int k = k0 + tx;
    int n = n0 + ty + 4 * kk;
    if (n < Npad && k < K) out[(long)n * K + k] = lds[tx][ty + 4 * kk];
  }
}

__global__ __launch_bounds__(256) void k_prep(
    const float* __restrict__ ent, const float* __restrict__ rel,
    const int* __restrict__ e_s, const int* __restrict__ q_s, const int* __restrict__ e_c,
    const float* __restrict__ W1w, const float* __restrict__ fc1w, const float* __restrict__ fcw,
    unsigned short* __restrict__ cat, unsigned short* __restrict__ rbuf,
    unsigned short* __restrict__ W1T, unsigned short* __restrict__ fc1T,
    unsigned short* __restrict__ fcwT) {
  __shared__ unsigned short lds[64][65];
  int blk = blockIdx.x, tid = threadIdx.x;
  if (blk < PREP_R2) {
    // gather+convert: cat[1024][400] (es|ec), rbuf[1024][200]
    int idx = blk * 256 + tid;
    if (idx < B_ * CATK) {
      int s = idx / CATK, i = idx - s * CATK;
      int row = (i < E_) ? e_s[s] : e_c[s];
      int col = (i < E_) ? i : i - E_;
      cat[idx] = f2bf(ent[row * E_ + col]);
    } else {
      int j = idx - B_ * CATK;   // < B_*E_ by region sizing
      int s = j / E_, i = j - s * E_;
      rbuf[j] = f2bf(rel[q_s[s] * E_ + i]);
    }
  } else if (blk < PREP_R3) {
    int l = blk - PREP_R2;
    transpose_region(W1w, W1T, 200, 208, CATK, l % 4, l / 4, lds);
  } else if (blk < PREP_R4) {
    int l = blk - PREP_R3;
    transpose_region(fc1w, fc1T, 288, 288, E_, l % 5, l / 5, lds);
  } else {
    int l = blk - PREP_R4;
    transpose_region(fcw, fcwT, 200, 208, FCIN, l % 4, l / 4, lds);
  }
}

// ---------------- shared 64x16 GEMM tile (4 waves; wave w = rows m0+16w..+15) ----------------
template<int NK, int RQ>
static __device__ __forceinline__ floatx4 gemm_64x16(
    const unsigned short* __restrict__ A, int lda,
    const unsigned short* __restrict__ Bt, int ldb, int m0, int n0) {
  int lane = threadIdx.x & 63;
  int wv   = threadIdx.x >> 6;
  int l16  = lane & 15, quad = lane >> 4;
  const unsigned short* ap = A  + (long)(m0 + 16 * wv + l16) * lda + quad * 8;
  const unsigned short* bp = Bt + (long)(n0 + l16) * ldb + quad * 8;
  floatx4 acc = {0.f, 0.f, 0.f, 0.f};
#pragma unroll 4
  for (int ks = 0; ks < NK; ks++) {
    short8 a = *(const short8*)(ap + ks * 32);
    short8 b = *(const short8*)(bp + ks * 32);
    acc = __builtin_amdgcn_mfma_f32_16x16x32_bf16(a, b, acc, 0, 0, 0);
  }
  if (RQ > 0) {  // K remainder: quads < RQ hold real data, rest contribute zeros
    short8 z = {0,0,0,0,0,0,0,0};
    short8 a = (quad < RQ) ? *(const short8*)(ap + NK * 32) : z;
    short8 b = (quad < RQ) ? *(const short8*)(bp + NK * 32) : z;
    acc = __builtin_amdgcn_mfma_f32_16x16x32_bf16(a, b, acc, 0, 0, 0);
  }
  return acc;
}

// ------- fused e1-GEMM + k-GEMM (independent; region by blockIdx) -------
__global__ __launch_bounds__(256) void k_gemm_ek(
    const unsigned short* __restrict__ cat, const unsigned short* __restrict__ W1T,
    const float* __restrict__ W1b,
    const float* __restrict__ g0, const float* __restrict__ b0,
    const float* __restrict__ m0p, const float* __restrict__ v0,
    unsigned short* __restrict__ xbuf,
    const unsigned short* __restrict__ rbuf, const unsigned short* __restrict__ fc1T,
    const float* __restrict__ fc1b,
    const float* __restrict__ g1, const float* __restrict__ v1,
    unsigned short* __restrict__ kbuf) {
  int blk = blockIdx.x;
  int lane = threadIdx.x & 63, wv = threadIdx.x >> 6;
  int l16 = lane & 15, quad = lane >> 4;
  if (blk < 208) {
    int m0 = (blk & 15) * 64, n0 = (blk >> 4) * 16;
    floatx4 acc = gemm_64x16<12, 2>(cat, CATK, W1T, CATK, m0, n0);
    int j = n0 + l16;
    if (j < E_) {
      float s0  = g0[0] * rsqrtf(v0[0] + 1e-5f);
      float off = (W1b[j] - m0p[0]) * s0 + b0[0];
      int rbase = m0 + 16 * wv + quad * 4;
#pragma unroll
      for (int i = 0; i < 4; i++)
        xbuf[(rbase + i) * E_ + j] = f2bf(acc[i] * s0 + off);
    }
  } else {
    int l = blk - 208;
    int m0 = (l & 15) * 64, n0 = (l >> 4) * 16;
    floatx4 acc = gemm_64x16<6, 1>(rbuf, E_, fc1T, E_, m0, n0);
    int c = n0 + l16;              // < 288 always (288 = 18*16)
    int o = c / FW_;
    float s1 = g1[o] * rsqrtf(v1[o] + 1e-5f);
    float fb = fc1b[c];
    int rbase = m0 + 16 * wv + quad * 4;
#pragma unroll
    for (int i = 0; i < 4; i++)
      kbuf[(rbase + i) * KDIM + c] = f2bf((acc[i] + fb) * s1);
  }
}

// ------- per-sample conv + bn1 bias -> flat ; PLUS entity fp32->bf16 cvt region -------
#define CVT_BLKS 9766   // ceil(2,500,000/256)
__global__ __launch_bounds__(256) void k_conv(
    const unsigned short* __restrict__ xbuf, const unsigned short* __restrict__ kbuf,
    const float* __restrict__ g1, const float* __restrict__ b1,
    const float* __restrict__ m1, const float* __restrict__ v1,
    unsigned short* __restrict__ flat,
    const float* __restrict__ ent, unsigned short* __restrict__ entb) {
  __shared__ float xs[E_];
  __shared__ float ks[KDIM];
  __shared__ float beta[OC_];
  int tid = threadIdx.x;
  if (blockIdx.x >= B_) {
    // ---- entity embedding fp32 -> bf16 (float4 in, ushort4 nt out) ----
    int i = (blockIdx.x - B_) * 256 + tid;
    if (i < NE_ * E_ / 4) {
      float4 v = ((const float4*)ent)[i];
      ushort4v o = {f2bf(v.x), f2bf(v.y), f2bf(v.z), f2bf(v.w)};
      __builtin_nontemporal_store(o, (ushort4v*)entb + i);
    }
    return;
  }
  int b = blockIdx.x;
  if (tid < E_)  xs[tid] = bf2f(xbuf[b * E_ + tid]);
  for (int i = tid; i < KDIM; i += 256) ks[i] = bf2f(kbuf[b * KDIM + i]);
  if (tid < OC_) {
    float s = g1[tid] * rsqrtf(v1[tid] + 1e-5f);
    beta[tid] = b1[tid] - m1[tid] * s;
  }
  __syncthreads();
  int o = tid >> 3, pc = tid & 7;
  int p0 = pc * 24;                         // 96 B aligned -> float4 LDS reads
  float kw[FW_];
#pragma unroll
  for (int w = 0; w < FW_; w++) kw[w] = ks[o * FW_ + w];
  float xw[32];                             // xs[p0 .. p0+31]
#pragma unroll
  for (int q = 0; q < 8; q++) {
    float4 v = *(const float4*)&xs[p0 + 4 * q];
    xw[4 * q + 0] = v.x; xw[4 * q + 1] = v.y; xw[4 * q + 2] = v.z; xw[4 * q + 3] = v.w;
  }
  float bo = beta[o];
  unsigned short* fp = flat + b * FCIN + o * WP_ + p0;
#pragma unroll
  for (int j = 0; j < 24; j += 2) {
    float a0 = bo, a1 = bo;
#pragma unroll
    for (int w = 0; w < FW_; w++) {
      a0 += xw[j + w] * kw[w];
      a1 += xw[j + 1 + w] * kw[w];
    }
    unsigned pack = (unsigned)f2bf(a0) | ((unsigned)f2bf(a1) << 16);
    *(unsigned*)(fp + j) = pack;            // offset even -> 4B aligned
  }
}

// ------------- flat @ fc_w with IN-BLOCK split-K x8 + fused bn2/relu epilogue -> hbuf -------------
__global__ __launch_bounds__(512) void k_gemm_fc2(
    const unsigned short* __restrict__ flat, const unsigned short* __restrict__ fcwT,
    const float* __restrict__ fcb,
    const float* __restrict__ g2, const float* __restrict__ b2,
    const float* __restrict__ m2, const float* __restrict__ v2,
    unsigned short* __restrict__ hbuf) {
  __shared__ float red[8][32][17];          // 17,408 B; +17 stride breaks bank aliasing
  int m0 = blockIdx.x * 32, n0 = blockIdx.y * 16;
  int tid = threadIdx.x;
  int lane = tid & 63, kc = tid >> 6;       // wave index = K-chunk index
  int l16 = lane & 15, quad = lane >> 4;
  const unsigned short* ap0 = flat + (long)(m0 + l16) * FCIN + kc * 768 + quad * 8;
  const unsigned short* ap1 = ap0 + 16 * FCIN;
  const unsigned short* bp  = fcwT + (long)(n0 + l16) * FCIN + kc * 768 + quad * 8;
  floatx4 acc0 = {0.f, 0.f, 0.f, 0.f};
  floatx4 acc1 = {0.f, 0.f, 0.f, 0.f};
#pragma unroll 4
  for (int ks = 0; ks < 24; ks++) {
    short8 b  = *(const short8*)(bp  + ks * 32);
    short8 a0 = *(const short8*)(ap0 + ks * 32);
    short8 a1 = *(const short8*)(ap1 + ks * 32);
    acc0 = __builtin_amdgcn_mfma_f32_16x16x32_bf16(a0, b, acc0, 0, 0, 0);
    acc1 = __builtin_amdgcn_mfma_f32_16x16x32_bf16(a1, b, acc1, 0, 0, 0);
  }
#pragma unroll
  for (int i = 0; i < 4; i++) {
    red[kc][quad * 4 + i][l16]      = acc0[i];
    red[kc][16 + quad * 4 + i][l16] = acc1[i];
  }
  __syncthreads();
  // 512 outputs (32 rows x 16 cols), one per thread; reduce in ascending kc order.
  int row = tid >> 4, col = tid & 15;
  float s = 0.f;
#pragma unroll
  for (int k2 = 0; k2 < 8; k2++) s += red[k2][row][col];
  int j = n0 + col;
  if (j < E_) {
    float s2 = g2[j] * rsqrtf(v2[j] + 1e-5f);
    float h = (s + fcb[j] - m2[j]) * s2 + b2[j];
    hbuf[(m0 + row) * E_ + j] = f2bf(fmaxf(h, 0.f));
  }
}

// ---------------- out = sigmoid(h @ entity^T + bias) -> d_out[1024][50000] fp32 ----------------
// 256m x 128n tile, 512 threads (8 waves). B tile staged once in LDS, fragment-major
// Blds[25 chunks][np(128)][8 bf16] = 51,200 B (K=200 = 25x8 exactly, no padding)
// -> 3 blocks/CU (was 2 at 57,344 B). Column map: np=(nf,j) -> col 4*j + (nf&3) + 64*(nf>>2),
// so lane l16's fragment group {nf=0..3} covers cols 4*l16..+3 and {nf=4..7} covers
// 64+4*l16..+3: every dwordx4 store instruction is a fully-DENSE 256 B run per 16-lane
// group (was 16B-at-32B-stride, 50% sector density, 1.36x HBM write amplification).
__global__ __launch_bounds__(512, 6) void k_gemm_out(
    const unsigned short* __restrict__ hbuf, const unsigned short* __restrict__ entb,
    const float* __restrict__ bias, float* __restrict__ out) {
  __shared__ __align__(16) unsigned short Blds[25 * 128 * 8];  // 51,200 B
  int g = blockIdx.x;                       // 0..1563
  int xcd = g & 7, local_ = g >> 3;         // dispatch round-robins XCDs
  int T = (xcd < 4 ? xcd * 196 : 784 + (xcd - 4) * 195) + local_;
  int mt = T & 3, nt = T >> 2;
  int m0 = mt * 256, n0 = nt * 128;
  int tid = threadIdx.x;

  // ---- stage B tile: 3200 chunks of 16 B (chunk c covers k=8c..8c+7, all real) ----
#pragma unroll
  for (int it = 0; it < 7; ++it) {
    int idx = it * 512 + tid;               // [c][np]
    if (idx < 25 * 128) {
      int c = idx >> 7, np = idx & 127;
      int col = 4 * (np & 15) + ((np >> 4) & 3) + 64 * (np >> 6);
      int n = n0 + col;
      int kb = c * 8;
      short8 v = {0, 0, 0, 0, 0, 0, 0, 0};
      if (n < NE_) v = *(const short8*)(entb + (long)n * E_ + kb);
      *(short8*)(Blds + idx * 8) = v;
    }
  }
  __syncthreads();

  int lane = tid & 63, wv = tid >> 6;       // wv 0..7
  int l16 = lane & 15, quad = lane >> 4;
  const unsigned short* ap0 = hbuf + (long)(m0 + wv * 32 + l16) * E_ + quad * 8;
  const unsigned short* ap1 = ap0 + 16 * E_;

  floatx4 acc[16];
#pragma unroll
  for (int i = 0; i < 16; ++i) acc[i] = (floatx4){0.f, 0.f, 0.f, 0.f};

#pragma unroll
  for (int ks = 0; ks < 6; ++ks) {
    short8 a0 = *(const short8*)(ap0 + ks * 32);
    short8 a1 = *(const short8*)(ap1 + ks * 32);
    const unsigned short* bb = Blds + (ks * 4 + quad) * 1024 + l16 * 8;
#pragma unroll
    for (int nf = 0; nf < 8; ++nf) {
      short8 b = *(const short8*)(bb + nf * 128);
      acc[nf]     = __builtin_amdgcn_mfma_f32_16x16x32_bf16(a0, b, acc[nf], 0, 0, 0);
      acc[8 + nf] = __builtin_amdgcn_mfma_f32_16x16x32_bf16(a1, b, acc[8 + nf], 0, 0, 0);
    }
  }
  { // k remainder 192..199 = chunk 24: A/B real on quad 0 only (a=0 elsewhere -> b moot)
    short8 z = {0, 0, 0, 0, 0, 0, 0, 0};
    short8 a0 = (quad == 0) ? *(const short8*)(ap0 + 192) : z;
    short8 a1 = (quad == 0) ? *(const short8*)(ap1 + 192) : z;
    const unsigned short* bbr = Blds + 24 * 1024 + l16 * 8;
#pragma unroll
    for (int nf = 0; nf < 8; ++nf) {
      short8 b = (quad == 0) ? *(const short8*)(bbr + nf * 128) : z;
      acc[nf]     = __builtin_amdgcn_mfma_f32_16x16x32_bf16(a0, b, acc[nf], 0, 0, 0);
      acc[8 + nf] = __builtin_amdgcn_mfma_f32_16x16x32_bf16(a1, b, acc[8 + nf], 0, 0, 0);
    }
  }

  int nb0 = n0 + 4 * l16;                   // fragment group 0 base col (4-aligned)
  int nb1 = nb0 + 64;                       // fragment group 1 base col
  bool ok0 = nb0 < NE_, ok1 = nb1 < NE_;    // NE%4==0 -> whole float4 valid or not
  float4 bi0 = ok0 ? *(const float4*)(bias + nb0) : make_float4(0.f, 0.f, 0.f, 0.f);
  float4 bi1 = ok1 ? *(const float4*)(bias + nb1) : make_float4(0.f, 0.f, 0.f, 0.f);
#pragma unroll
  for (int mf = 0; mf < 2; ++mf) {
#pragma unroll
    for (int i = 0; i < 4; ++i) {
      int row = m0 + wv * 32 + mf * 16 + quad * 4 + i;
      floatx4 v0, v1;
      v0.x = 1.f / (1.f + __expf(-(acc[mf * 8 + 0][i] + bi0.x)));
      v0.y = 1.f / (1.f + __expf(-(acc[mf * 8 + 1][i] + bi0.y)));
      v0.z = 1.f / (1.f + __expf(-(acc[mf * 8 + 2][i] + bi0.z)));
      v0.w = 1.f / (1.f + __expf(-(acc[mf * 8 + 3][i] + bi0.w)));
      v1.x = 1.f / (1.f + __expf(-(acc[mf * 8 + 4][i] + bi1.x)));
      v1.y = 1.f / (1.f + __expf(-(acc[mf * 8 + 5][i] + bi1.y)));
      v1.z = 1.f / (1.f + __expf(-(acc[mf * 8 + 6][i] + bi1.z)));
      v1.w = 1.f / (1.f + __expf(-(acc[mf * 8 + 7][i] + bi1.w)));
      float* op = out + (long)row * NE_;
      if (ok0) __builtin_nontemporal_store(v0, (floatx4*)(op + nb0));
      if (ok1) __builtin_nontemporal_store(v1, (floatx4*)(op + nb1));
    }
  }
}

extern "C" void kernel_launch(void* const* d_in, const int* in_sizes, int n_in,
                              void* d_out, int out_size, void* d_ws, size_t ws_size,
                              hipStream_t stream) {
  const int* e_s = (const int*)d_in[0];
  const int* q_s = (const int*)d_in[1];
  const int* e_c = (const int*)d_in[2];
  const float* ent  = (const float*)d_in[3];
  const float* rel  = (const float*)d_in[4];
  const float* W1w  = (const float*)d_in[5];
  const float* W1b  = (const float*)d_in[6];
  const float* fc1w = (const float*)d_in[7];
  const float* fc1b = (const float*)d_in[8];
  const float* fcw  = (const float*)d_in[9];
  const float* fcb  = (const float*)d_in[10];
  const float* g0 = (const float*)d_in[11];
  const float* b0 = (const float*)d_in[12];
  const float* m0 = (const float*)d_in[13];
  const float* v0 = (const float*)d_in[14];
  const float* g1 = (const float*)d_in[15];
  const float* b1 = (const float*)d_in[16];
  const float* m1 = (const float*)d_in[17];
  const float* v1 = (const float*)d_in[18];
  const float* g2 = (const float*)d_in[19];
  const float* b2 = (const float*)d_in[20];
  const float* m2 = (const float*)d_in[21];
  const float* v2 = (const float*)d_in[22];
  const float* bias = (const float*)d_in[23];
  float* out = (float*)d_out;

  // Workspace layout (256 B padded regions)
  char* w = (char*)d_ws;
  unsigned short* entb = (unsigned short*)(w + 0);          // 20,000,000 B [50000][200]
  unsigned short* cat  = (unsigned short*)(w + 20000256);   //    819,200 B [1024][400]
  unsigned short* rbuf = (unsigned short*)(w + 20819712);   //    409,600 B [1024][200]
  unsigned short* W1T  = (unsigned short*)(w + 21229568);   //    166,400 B [208][400]
  unsigned short* fc1T = (unsigned short*)(w + 21396224);   //    115,200 B [288][200]
  unsigned short* fcwT = (unsigned short*)(w + 21511680);   //  2,555,904 B [208][6144]
  unsigned short* xbuf = (unsigned short*)(w + 24067840);   //    409,600 B [1024][200]
  unsigned short* kbuf = (unsigned short*)(w + 24477696);   //    589,824 B [1024][288]
  unsigned short* flat = (unsigned short*)(w + 25067776);   // 12,582,912 B [1024][6144]
  unsigned short* hbuf = (unsigned short*)(w + 37650944);   //    409,600 B [1024][200]
  // end = 38,060,544

  k_prep<<<dim3(PREP_TOTAL), dim3(256), 0, stream>>>(
      ent, rel, e_s, q_s, e_c, W1w, fc1w, fcw, cat, rbuf, W1T, fc1T, fcwT);
  k_gemm_ek<<<dim3(496), dim3(256), 0, stream>>>(
      cat, W1T, W1b, g0, b0, m0, v0, xbuf, rbuf, fc1T, fc1b, g1, v1, kbuf);
  k_conv<<<dim3(B_ + CVT_BLKS), dim3(256), 0, stream>>>(
      xbuf, kbuf, g1, b1, m1, v1, flat, ent, entb);
  k_gemm_fc2<<<dim3(32, 13), dim3(512), 0, stream>>>(
      flat, fcwT, fcb, g2, b2, m2, v2, hbuf);
  k_gemm_out<<<dim3(1564), dim3(512), 0, stream>>>(hbuf, entb, bias, out);
}

// Round 6
// 390.493 us; speedup vs baseline: 1.2421x; 1.2421x over previous
//
#include <hip/hip_runtime.h>

// Problem constants
#define B_   1024
#define E_   200
#define NE_  50000
#define OC_  32
#define FW_  9
#define WP_  192
#define FCIN 6144   // OC*WP
#define CATK 400    // E+R
#define KDIM 288    // OC*FW

typedef __attribute__((ext_vector_type(8))) short short8;
typedef __attribute__((ext_vector_type(4))) float floatx4;
typedef __attribute__((ext_vector_type(4))) unsigned short ushort4v;

static __device__ __forceinline__ float bf2f(unsigned short u) {
  return __uint_as_float(((unsigned)u) << 16);
}
static __device__ __forceinline__ unsigned short f2bf(float f) {
  unsigned u = __float_as_uint(f);
  u += 0x7FFFu + ((u >> 16) & 1u);   // RNE
  return (unsigned short)(u >> 16);
}

// ---------------- fused prep: gather + 3 transposes (entity cvt moved to k_conv) ----------------
#define PREP_GATH_BLKS  2400   // (B*CATK + B*E)/256 exactly
#define PREP_W1_BLKS    28     // (4 x 7)
#define PREP_FC1_BLKS   20     // (5 x 4)
#define PREP_FCW_BLKS   384    // (4 x 96)
#define PREP_R2 (PREP_GATH_BLKS)
#define PREP_R3 (PREP_R2 + PREP_W1_BLKS)
#define PREP_R4 (PREP_R3 + PREP_FC1_BLKS)
#define PREP_TOTAL (PREP_R4 + PREP_FCW_BLKS)   // 2832

// LDS tile transpose+pad+convert: in[k*N+n] fp32 -> out[n*K+k] bf16 (n<Npad).
static __device__ __forceinline__ void transpose_region(
    const float* __restrict__ in, unsigned short* __restrict__ out,
    int N, int Npad, int K, int bx, int by,
    unsigned short (*lds)[65]) {
  int n0 = bx * 64, k0 = by * 64;
  int tx = threadIdx.x & 63, ty = threadIdx.x >> 6;   // ty in 0..3
#pragma unroll
  for (int kk = 0; kk < 16; kk++) {
    int k = k0 + ty + 4 * kk;
    int n = n0 + tx;
    unsigned short v = 0;
    if (k < K && n < N) v = f2bf(in[(long)k * N + n]);
    lds[ty + 4 * kk][tx] = v;
  }
  __syncthreads();
#pragma unroll
  for (int kk = 0; kk < 16; kk++) {
    int k = k0 + tx;
    int n = n0 + ty + 4 * kk;
    if (n < Npad && k < K) out[(long)n * K + k] = lds[tx][ty + 4 * kk];
  }
}

__global__ __launch_bounds__(256) void k_prep(
    const float* __restrict__ ent, const float* __restrict__ rel,
    const int* __restrict__ e_s, const int* __restrict__ q_s, const int* __restrict__ e_c,
    const float* __restrict__ W1w, const float* __restrict__ fc1w, const float* __restrict__ fcw,
    unsigned short* __restrict__ cat, unsigned short* __restrict__ rbuf,
    unsigned short* __restrict__ W1T, unsigned short* __restrict__ fc1T,
    unsigned short* __restrict__ fcwT) {
  __shared__ unsigned short lds[64][65];
  int blk = blockIdx.x, tid = threadIdx.x;
  if (blk < PREP_R2) {
    // gather+convert: cat[1024][400] (es|ec), rbuf[1024][200]
    int idx = blk * 256 + tid;
    if (idx < B_ * CATK) {
      int s = idx / CATK, i = idx - s * CATK;
      int row = (i < E_) ? e_s[s] : e_c[s];
      int col = (i < E_) ? i : i - E_;
      cat[idx] = f2bf(ent[row * E_ + col]);
    } else {
      int j = idx - B_ * CATK;   // < B_*E_ by region sizing
      int s = j / E_, i = j - s * E_;
      rbuf[j] = f2bf(rel[q_s[s] * E_ + i]);
    }
  } else if (blk < PREP_R3) {
    int l = blk - PREP_R2;
    transpose_region(W1w, W1T, 200, 208, CATK, l % 4, l / 4, lds);
  } else if (blk < PREP_R4) {
    int l = blk - PREP_R3;
    transpose_region(fc1w, fc1T, 288, 288, E_, l % 5, l / 5, lds);
  } else {
    int l = blk - PREP_R4;
    transpose_region(fcw, fcwT, 200, 208, FCIN, l % 4, l / 4, lds);
  }
}

// ---------------- shared 64x16 GEMM tile (4 waves; wave w = rows m0+16w..+15) ----------------
template<int NK, int RQ>
static __device__ __forceinline__ floatx4 gemm_64x16(
    const unsigned short* __restrict__ A, int lda,
    const unsigned short* __restrict__ Bt, int ldb, int m0, int n0) {
  int lane = threadIdx.x & 63;
  int wv   = threadIdx.x >> 6;
  int l16  = lane & 15, quad = lane >> 4;
  const unsigned short* ap = A  + (long)(m0 + 16 * wv + l16) * lda + quad * 8;
  const unsigned short* bp = Bt + (long)(n0 + l16) * ldb + quad * 8;
  floatx4 acc = {0.f, 0.f, 0.f, 0.f};
#pragma unroll 4
  for (int ks = 0; ks < NK; ks++) {
    short8 a = *(const short8*)(ap + ks * 32);
    short8 b = *(const short8*)(bp + ks * 32);
    acc = __builtin_amdgcn_mfma_f32_16x16x32_bf16(a, b, acc, 0, 0, 0);
  }
  if (RQ > 0) {  // K remainder: quads < RQ hold real data, rest contribute zeros
    short8 z = {0,0,0,0,0,0,0,0};
    short8 a = (quad < RQ) ? *(const short8*)(ap + NK * 32) : z;
    short8 b = (quad < RQ) ? *(const short8*)(bp + NK * 32) : z;
    acc = __builtin_amdgcn_mfma_f32_16x16x32_bf16(a, b, acc, 0, 0, 0);
  }
  return acc;
}

// ------- fused e1-GEMM + k-GEMM (independent; region by blockIdx) -------
__global__ __launch_bounds__(256) void k_gemm_ek(
    const unsigned short* __restrict__ cat, const unsigned short* __restrict__ W1T,
    const float* __restrict__ W1b,
    const float* __restrict__ g0, const float* __restrict__ b0,
    const float* __restrict__ m0p, const float* __restrict__ v0,
    unsigned short* __restrict__ xbuf,
    const unsigned short* __restrict__ rbuf, const unsigned short* __restrict__ fc1T,
    const float* __restrict__ fc1b,
    const float* __restrict__ g1, const float* __restrict__ v1,
    unsigned short* __restrict__ kbuf) {
  int blk = blockIdx.x;
  int lane = threadIdx.x & 63, wv = threadIdx.x >> 6;
  int l16 = lane & 15, quad = lane >> 4;
  if (blk < 208) {
    int m0 = (blk & 15) * 64, n0 = (blk >> 4) * 16;
    floatx4 acc = gemm_64x16<12, 2>(cat, CATK, W1T, CATK, m0, n0);
    int j = n0 + l16;
    if (j < E_) {
      float s0  = g0[0] * rsqrtf(v0[0] + 1e-5f);
      float off = (W1b[j] - m0p[0]) * s0 + b0[0];
      int rbase = m0 + 16 * wv + quad * 4;
#pragma unroll
      for (int i = 0; i < 4; i++)
        xbuf[(rbase + i) * E_ + j] = f2bf(acc[i] * s0 + off);
    }
  } else {
    int l = blk - 208;
    int m0 = (l & 15) * 64, n0 = (l >> 4) * 16;
    floatx4 acc = gemm_64x16<6, 1>(rbuf, E_, fc1T, E_, m0, n0);
    int c = n0 + l16;              // < 288 always (288 = 18*16)
    int o = c / FW_;
    float s1 = g1[o] * rsqrtf(v1[o] + 1e-5f);
    float fb = fc1b[c];
    int rbase = m0 + 16 * wv + quad * 4;
#pragma unroll
    for (int i = 0; i < 4; i++)
      kbuf[(rbase + i) * KDIM + c] = f2bf((acc[i] + fb) * s1);
  }
}

// ------- per-sample conv + bn1 bias -> flat ; PLUS entity fp32->bf16 cvt region -------
#define CVT_BLKS 9766   // ceil(2,500,000/256)
__global__ __launch_bounds__(256) void k_conv(
    const unsigned short* __restrict__ xbuf, const unsigned short* __restrict__ kbuf,
    const float* __restrict__ g1, const float* __restrict__ b1,
    const float* __restrict__ m1, const float* __restrict__ v1,
    unsigned short* __restrict__ flat,
    const float* __restrict__ ent, unsigned short* __restrict__ entb) {
  __shared__ float xs[E_];
  __shared__ float ks[KDIM];
  __shared__ float beta[OC_];
  int tid = threadIdx.x;
  if (blockIdx.x >= B_) {
    // ---- entity embedding fp32 -> bf16 (float4 in, ushort4 nt out) ----
    int i = (blockIdx.x - B_) * 256 + tid;
    if (i < NE_ * E_ / 4) {
      float4 v = ((const float4*)ent)[i];
      ushort4v o = {f2bf(v.x), f2bf(v.y), f2bf(v.z), f2bf(v.w)};
      __builtin_nontemporal_store(o, (ushort4v*)entb + i);
    }
    return;
  }
  int b = blockIdx.x;
  if (tid < E_)  xs[tid] = bf2f(xbuf[b * E_ + tid]);
  for (int i = tid; i < KDIM; i += 256) ks[i] = bf2f(kbuf[b * KDIM + i]);
  if (tid < OC_) {
    float s = g1[tid] * rsqrtf(v1[tid] + 1e-5f);
    beta[tid] = b1[tid] - m1[tid] * s;
  }
  __syncthreads();
  int o = tid >> 3, pc = tid & 7;
  int p0 = pc * 24;                         // 96 B aligned -> float4 LDS reads
  float kw[FW_];
#pragma unroll
  for (int w = 0; w < FW_; w++) kw[w] = ks[o * FW_ + w];
  float xw[32];                             // xs[p0 .. p0+31]
#pragma unroll
  for (int q = 0; q < 8; q++) {
    float4 v = *(const float4*)&xs[p0 + 4 * q];
    xw[4 * q + 0] = v.x; xw[4 * q + 1] = v.y; xw[4 * q + 2] = v.z; xw[4 * q + 3] = v.w;
  }
  float bo = beta[o];
  unsigned short* fp = flat + b * FCIN + o * WP_ + p0;
#pragma unroll
  for (int j = 0; j < 24; j += 2) {
    float a0 = bo, a1 = bo;
#pragma unroll
    for (int w = 0; w < FW_; w++) {
      a0 += xw[j + w] * kw[w];
      a1 += xw[j + 1 + w] * kw[w];
    }
    unsigned pack = (unsigned)f2bf(a0) | ((unsigned)f2bf(a1) << 16);
    *(unsigned*)(fp + j) = pack;            // offset even -> 4B aligned
  }
}

// ------------- flat @ fc_w with IN-BLOCK split-K x8 + fused bn2/relu epilogue -> hbuf -------------
__global__ __launch_bounds__(512) void k_gemm_fc2(
    const unsigned short* __restrict__ flat, const unsigned short* __restrict__ fcwT,
    const float* __restrict__ fcb,
    const float* __restrict__ g2, const float* __restrict__ b2,
    const float* __restrict__ m2, const float* __restrict__ v2,
    unsigned short* __restrict__ hbuf) {
  __shared__ float red[8][32][17];          // 17,408 B; +17 stride breaks bank aliasing
  int m0 = blockIdx.x * 32, n0 = blockIdx.y * 16;
  int tid = threadIdx.x;
  int lane = tid & 63, kc = tid >> 6;       // wave index = K-chunk index
  int l16 = lane & 15, quad = lane >> 4;
  const unsigned short* ap0 = flat + (long)(m0 + l16) * FCIN + kc * 768 + quad * 8;
  const unsigned short* ap1 = ap0 + 16 * FCIN;
  const unsigned short* bp  = fcwT + (long)(n0 + l16) * FCIN + kc * 768 + quad * 8;
  floatx4 acc0 = {0.f, 0.f, 0.f, 0.f};
  floatx4 acc1 = {0.f, 0.f, 0.f, 0.f};
#pragma unroll 4
  for (int ks = 0; ks < 24; ks++) {
    short8 b  = *(const short8*)(bp  + ks * 32);
    short8 a0 = *(const short8*)(ap0 + ks * 32);
    short8 a1 = *(const short8*)(ap1 + ks * 32);
    acc0 = __builtin_amdgcn_mfma_f32_16x16x32_bf16(a0, b, acc0, 0, 0, 0);
    acc1 = __builtin_amdgcn_mfma_f32_16x16x32_bf16(a1, b, acc1, 0, 0, 0);
  }
#pragma unroll
  for (int i = 0; i < 4; i++) {
    red[kc][quad * 4 + i][l16]      = acc0[i];
    red[kc][16 + quad * 4 + i][l16] = acc1[i];
  }
  __syncthreads();
  // 512 outputs (32 rows x 16 cols), one per thread; reduce in ascending kc order.
  int row = tid >> 4, col = tid & 15;
  float s = 0.f;
#pragma unroll
  for (int k2 = 0; k2 < 8; k2++) s += red[k2][row][col];
  int j = n0 + col;
  if (j < E_) {
    float s2 = g2[j] * rsqrtf(v2[j] + 1e-5f);
    float h = (s + fcb[j] - m2[j]) * s2 + b2[j];
    hbuf[(m0 + row) * E_ + j] = f2bf(fmaxf(h, 0.f));
  }
}

// ---------------- out = sigmoid(h @ entity^T + bias) -> d_out[1024][50000] fp32 ----------------
// 256m x 128n tile, 512 threads (8 waves). B tile staged once in LDS, fragment-major
// Blds[25 chunks][np(128)][8 bf16] = 51,200 B (K=200 = 25x8 exactly, no padding).
// Column map: np=(nf,j) -> col 4*j + (nf&3) + 64*(nf>>2): every dwordx4 store is a
// fully-DENSE 256 B run per 16-lane group (full 128 B lines -> nt-store safe).
// launch_bounds(512,4): 128-VGPR cap, 2 blocks/CU. (512,6) spilled acc[16] to scratch
// (+205 MB writes +120 MB reads, VGPR 60->40, 192 us) -- accumulator footprint
// (64 VGPR) makes >4 waves/EU arithmetically impossible without spills.
__global__ __launch_bounds__(512, 4) void k_gemm_out(
    const unsigned short* __restrict__ hbuf, const unsigned short* __restrict__ entb,
    const float* __restrict__ bias, float* __restrict__ out) {
  __shared__ __align__(16) unsigned short Blds[25 * 128 * 8];  // 51,200 B
  int g = blockIdx.x;                       // 0..1563
  int xcd = g & 7, local_ = g >> 3;         // dispatch round-robins XCDs
  int T = (xcd < 4 ? xcd * 196 : 784 + (xcd - 4) * 195) + local_;
  int mt = T & 3, nt = T >> 2;
  int m0 = mt * 256, n0 = nt * 128;
  int tid = threadIdx.x;

  // ---- stage B tile: 3200 chunks of 16 B (chunk c covers k=8c..8c+7, all real) ----
#pragma unroll
  for (int it = 0; it < 7; ++it) {
    int idx = it * 512 + tid;               // [c][np]
    if (idx < 25 * 128) {
      int c = idx >> 7, np = idx & 127;
      int col = 4 * (np & 15) + ((np >> 4) & 3) + 64 * (np >> 6);
      int n = n0 + col;
      int kb = c * 8;
      short8 v = {0, 0, 0, 0, 0, 0, 0, 0};
      if (n < NE_) v = *(const short8*)(entb + (long)n * E_ + kb);
      *(short8*)(Blds + idx * 8) = v;
    }
  }
  __syncthreads();

  int lane = tid & 63, wv = tid >> 6;       // wv 0..7
  int l16 = lane & 15, quad = lane >> 4;
  const unsigned short* ap0 = hbuf + (long)(m0 + wv * 32 + l16) * E_ + quad * 8;
  const unsigned short* ap1 = ap0 + 16 * E_;

  floatx4 acc[16];
#pragma unroll
  for (int i = 0; i < 16; ++i) acc[i] = (floatx4){0.f, 0.f, 0.f, 0.f};

#pragma unroll
  for (int ks = 0; ks < 6; ++ks) {
    short8 a0 = *(const short8*)(ap0 + ks * 32);
    short8 a1 = *(const short8*)(ap1 + ks * 32);
    const unsigned short* bb = Blds + (ks * 4 + quad) * 1024 + l16 * 8;
#pragma unroll
    for (int nf = 0; nf < 8; ++nf) {
      short8 b = *(const short8*)(bb + nf * 128);
      acc[nf]     = __builtin_amdgcn_mfma_f32_16x16x32_bf16(a0, b, acc[nf], 0, 0, 0);
      acc[8 + nf] = __builtin_amdgcn_mfma_f32_16x16x32_bf16(a1, b, acc[8 + nf], 0, 0, 0);
    }
  }
  { // k remainder 192..199 = chunk 24: A/B real on quad 0 only (a=0 elsewhere -> b moot)
    short8 z = {0, 0, 0, 0, 0, 0, 0, 0};
    short8 a0 = (quad == 0) ? *(const short8*)(ap0 + 192) : z;
    short8 a1 = (quad == 0) ? *(const short8*)(ap1 + 192) : z;
    const unsigned short* bbr = Blds + 24 * 1024 + l16 * 8;
#pragma unroll
    for (int nf = 0; nf < 8; ++nf) {
      short8 b = (quad == 0) ? *(const short8*)(bbr + nf * 128) : z;
      acc[nf]     = __builtin_amdgcn_mfma_f32_16x16x32_bf16(a0, b, acc[nf], 0, 0, 0);
      acc[8 + nf] = __builtin_amdgcn_mfma_f32_16x16x32_bf16(a1, b, acc[8 + nf], 0, 0, 0);
    }
  }

  int nb0 = n0 + 4 * l16;                   // fragment group 0 base col (4-aligned)
  int nb1 = nb0 + 64;                       // fragment group 1 base col
  bool ok0 = nb0 < NE_, ok1 = nb1 < NE_;    // NE%4==0 -> whole float4 valid or not
  float4 bi0 = ok0 ? *(const float4*)(bias + nb0) : make_float4(0.f, 0.f, 0.f, 0.f);
  float4 bi1 = ok1 ? *(const float4*)(bias + nb1) : make_float4(0.f, 0.f, 0.f, 0.f);
#pragma unroll
  for (int mf = 0; mf < 2; ++mf) {
#pragma unroll
    for (int i = 0; i < 4; ++i) {
      int row = m0 + wv * 32 + mf * 16 + quad * 4 + i;
      floatx4 v0, v1;
      v0.x = 1.f / (1.f + __expf(-(acc[mf * 8 + 0][i] + bi0.x)));
      v0.y = 1.f / (1.f + __expf(-(acc[mf * 8 + 1][i] + bi0.y)));
      v0.z = 1.f / (1.f + __expf(-(acc[mf * 8 + 2][i] + bi0.z)));
      v0.w = 1.f / (1.f + __expf(-(acc[mf * 8 + 3][i] + bi0.w)));
      v1.x = 1.f / (1.f + __expf(-(acc[mf * 8 + 4][i] + bi1.x)));
      v1.y = 1.f / (1.f + __expf(-(acc[mf * 8 + 5][i] + bi1.y)));
      v1.z = 1.f / (1.f + __expf(-(acc[mf * 8 + 6][i] + bi1.z)));
      v1.w = 1.f / (1.f + __expf(-(acc[mf * 8 + 7][i] + bi1.w)));
      float* op = out + (long)row * NE_;
      if (ok0) __builtin_nontemporal_store(v0, (floatx4*)(op + nb0));
      if (ok1) __builtin_nontemporal_store(v1, (floatx4*)(op + nb1));
    }
  }
}

extern "C" void kernel_launch(void* const* d_in, const int* in_sizes, int n_in,
                              void* d_out, int out_size, void* d_ws, size_t ws_size,
                              hipStream_t stream) {
  const int* e_s = (const int*)d_in[0];
  const int* q_s = (const int*)d_in[1];
  const int* e_c = (const int*)d_in[2];
  const float* ent  = (const float*)d_in[3];
  const float* rel  = (const float*)d_in[4];
  const float* W1w  = (const float*)d_in[5];
  const float* W1b  = (const float*)d_in[6];
  const float* fc1w = (const float*)d_in[7];
  const float* fc1b = (const float*)d_in[8];
  const float* fcw  = (const float*)d_in[9];
  const float* fcb  = (const float*)d_in[10];
  const float* g0 = (const float*)d_in[11];
  const float* b0 = (const float*)d_in[12];
  const float* m0 = (const float*)d_in[13];
  const float* v0 = (const float*)d_in[14];
  const float* g1 = (const float*)d_in[15];
  const float* b1 = (const float*)d_in[16];
  const float* m1 = (const float*)d_in[17];
  const float* v1 = (const float*)d_in[18];
  const float* g2 = (const float*)d_in[19];
  const float* b2 = (const float*)d_in[20];
  const float* m2 = (const float*)d_in[21];
  const float* v2 = (const float*)d_in[22];
  const float* bias = (const float*)d_in[23];
  float* out = (float*)d_out;

  // Workspace layout (256 B padded regions)
  char* w = (char*)d_ws;
  unsigned short* entb = (unsigned short*)(w + 0);          // 20,000,000 B [50000][200]
  unsigned short* cat  = (unsigned short*)(w + 20000256);   //    819,200 B [1024][400]
  unsigned short* rbuf = (unsigned short*)(w + 20819712);   //    409,600 B [1024][200]
  unsigned short* W1T  = (unsigned short*)(w + 21229568);   //    166,400 B [208][400]
  unsigned short* fc1T = (unsigned short*)(w + 21396224);   //    115,200 B [288][200]
  unsigned short* fcwT = (unsigned short*)(w + 21511680);   //  2,555,904 B [208][6144]
  unsigned short* xbuf = (unsigned short*)(w + 24067840);   //    409,600 B [1024][200]
  unsigned short* kbuf = (unsigned short*)(w + 24477696);   //    589,824 B [1024][288]
  unsigned short* flat = (unsigned short*)(w + 25067776);   // 12,582,912 B [1024][6144]
  unsigned short* hbuf = (unsigned short*)(w + 37650944);   //    409,600 B [1024][200]
  // end = 38,060,544

  k_prep<<<dim3(PREP_TOTAL), dim3(256), 0, stream>>>(
      ent, rel, e_s, q_s, e_c, W1w, fc1w, fcw, cat, rbuf, W1T, fc1T, fcwT);
  k_gemm_ek<<<dim3(496), dim3(256), 0, stream>>>(
      cat, W1T, W1b, g0, b0, m0, v0, xbuf, rbuf, fc1T, fc1b, g1, v1, kbuf);
  k_conv<<<dim3(B_ + CVT_BLKS), dim3(256), 0, stream>>>(
      xbuf, kbuf, g1, b1, m1, v1, flat, ent, entb);
  k_gemm_fc2<<<dim3(32, 13), dim3(512), 0, stream>>>(
      flat, fcwT, fcb, g2, b2, m2, v2, hbuf);
  k_gemm_out<<<dim3(1564), dim3(512), 0, stream>>>(hbuf, entb, bias, out);
}